// Round 3
// baseline (278.519 us; speedup 1.0000x reference)
//
#include <hip/hip_runtime.h>

#define DEV __device__ __forceinline__

typedef __bf16 bf16;
typedef __bf16 bf16x4 __attribute__((ext_vector_type(4)));
typedef __bf16 bf16x8 __attribute__((ext_vector_type(8)));
typedef float f32x4 __attribute__((ext_vector_type(4)));

// Problem sizes
constexpr int BB = 16, LE = 512, LD = 128, DD = 1024;
constexpr int MALL = BB * LE;   // 8192 encoder rows total
constexpr int K4 = 4 * DD;      // 4096 feature dim

// ---- workspace layout (bytes) ----
constexpr size_t OFF_FEATS = 0;                                   // bf16 [8192][4096]
constexpr size_t OFF_HQW3  = OFF_FEATS + (size_t)MALL * K4 * 2;   // bf16 [2048][1024]  (hq * w3)
constexpr size_t OFF_HQT   = OFF_HQW3 + (size_t)BB * LD * DD * 2; // bf16 [16][1024][128] (hq^T)
constexpr size_t OFF_WT    = OFF_HQT + (size_t)BB * DD * LD * 2;  // bf16 [1024][4096]  (W_qv^T)
constexpr size_t OFF_ABF   = OFF_WT + (size_t)K4 * DD * 2;        // bf16 [8192][128]   (softmax A)
constexpr size_t OFF_S1    = OFF_ABF + (size_t)MALL * LD * 2;     // f32  [8192]
constexpr size_t OFF_S2    = OFF_S1 + (size_t)MALL * 4;           // f32  [2048]
constexpr size_t OFF_MROW  = OFF_S2 + (size_t)BB * LD * 4;        // f32  [8192]
constexpr size_t OFF_HCBAR = OFF_MROW + (size_t)MALL * 4;         // f32  [16][1024]
// total ~82.1 MB

// async global->LDS, 16B per lane; LDS dest is wave-uniform base (HW adds lane*16)
DEV void gload16(const void* g, void* l) {
  __builtin_amdgcn_global_load_lds(
      (const __attribute__((address_space(1))) void*)g,
      (__attribute__((address_space(3))) void*)l, 16, 0, 0);
}

// ---------------- prep: hc -> feats q0 (bf16) + s1 ; hq -> hq*w3 (bf16) + s2 -------------
__global__ __launch_bounds__(256) void k_prep(const float* __restrict__ hc,
                                              const float* __restrict__ hq,
                                              const float* __restrict__ wsim,
                                              bf16* __restrict__ feats,
                                              bf16* __restrict__ hqw3,
                                              float* __restrict__ s1,
                                              float* __restrict__ s2) {
  const int r = blockIdx.x;
  const int t = threadIdx.x;
  __shared__ float red[4];
  float dot;
  if (r < MALL) {
    const float4 v = reinterpret_cast<const float4*>(hc + (size_t)r * DD)[t];
    const float4 w = reinterpret_cast<const float4*>(wsim)[t];  // w1
    bf16x4 o; o[0] = (bf16)v.x; o[1] = (bf16)v.y; o[2] = (bf16)v.z; o[3] = (bf16)v.w;
    *reinterpret_cast<bf16x4*>(feats + (size_t)r * K4 + t * 4) = o;
    dot = v.x * w.x + v.y * w.y + v.z * w.z + v.w * w.w;
  } else {
    const int rw = r - MALL;  // 0..2047
    const float4 v = reinterpret_cast<const float4*>(hq + (size_t)rw * DD)[t];
    const float4 w2 = reinterpret_cast<const float4*>(wsim + DD)[t];
    const float4 w3 = reinterpret_cast<const float4*>(wsim + 2 * DD)[t];
    bf16x4 o; o[0] = (bf16)(v.x * w3.x); o[1] = (bf16)(v.y * w3.y);
    o[2] = (bf16)(v.z * w3.z); o[3] = (bf16)(v.w * w3.w);
    *reinterpret_cast<bf16x4*>(hqw3 + (size_t)rw * DD + t * 4) = o;
    dot = v.x * w2.x + v.y * w2.y + v.z * w2.z + v.w * w2.w;
  }
  #pragma unroll
  for (int o = 32; o; o >>= 1) dot += __shfl_down(dot, o);
  const int lane = t & 63, w = t >> 6;
  if (lane == 0) red[w] = dot;
  __syncthreads();
  if (t == 0) {
    float s = red[0] + red[1] + red[2] + red[3];
    if (r < MALL) s1[r] = s; else s2[r - MALL] = s;
  }
}

// ---------------- transpose f32 (R x C) -> bf16 (C x R), 64x64 LDS tiles -----------------
__global__ __launch_bounds__(256) void k_transpose(const float* __restrict__ in,
                                                   bf16* __restrict__ out,
                                                   int R, int C, long ibs, long obs) {
  __shared__ float tile[64][68];
  const float* inp = in + (size_t)blockIdx.z * ibs;
  bf16* outp = out + (size_t)blockIdx.z * obs;
  const int r0 = blockIdx.y * 64, c0 = blockIdx.x * 64;
  const int t = threadIdx.x;
  // load full 64x64 tile: 4 iters x 256 threads x float4
  #pragma unroll
  for (int i = 0; i < 4; i++) {
    const int r = i * 16 + (t >> 4), c = (t & 15) << 2;
    const float4 v = *reinterpret_cast<const float4*>(inp + (size_t)(r0 + r) * C + c0 + c);
    tile[r][c] = v.x; tile[r][c + 1] = v.y; tile[r][c + 2] = v.z; tile[r][c + 3] = v.w;
  }
  __syncthreads();
  {
    const int oc = t >> 2;  // out row within tile (source col)
    const int g = t & 3;    // 16-wide group along source rows
    bf16x8 t0, t1;
    #pragma unroll
    for (int i = 0; i < 8; i++) t0[i] = (bf16)tile[g * 16 + i][oc];
    #pragma unroll
    for (int i = 0; i < 8; i++) t1[i] = (bf16)tile[g * 16 + 8 + i][oc];
    bf16* op = outp + (size_t)(c0 + oc) * R + r0 + g * 16;
    *reinterpret_cast<bf16x8*>(op) = t0;
    *reinterpret_cast<bf16x8*>(op + 8) = t1;
  }
}

// ---------------- shared 128x128 MFMA NT GEMM core (m97 structure) -----------------------
// C[m][n] = sum_k A[m][k] * B[n][k] ; lda/ldb in elements; K = KTILES*64
// smem: first 32768 bytes used (As 16KB + Bs 16KB). Ends with __syncthreads().
template <int KTILES>
DEV void gemm_core(char* smem,
                   const bf16* __restrict__ Ag, int lda,
                   const bf16* __restrict__ Bg, int ldb,
                   f32x4 acc[4][4]) {
  bf16* As = (bf16*)smem;
  bf16* Bs = (bf16*)(smem + 16384);
  const int t = threadIdx.x;
  const int lane = t & 63;
  const int w = t >> 6;
  const int wm = w >> 1, wn = w & 1;
  const int l8 = lane >> 3, lc = lane & 7;
  const int ar = lane & 15;
  const int ak = (lane >> 4) * 8;
  const f32x4 zero = {0.f, 0.f, 0.f, 0.f};
  #pragma unroll
  for (int i = 0; i < 4; i++)
    #pragma unroll
    for (int j = 0; j < 4; j++) acc[i][j] = zero;

  for (int kt = 0; kt < KTILES; kt++) {
    const int k0 = kt * 64;
    #pragma unroll
    for (int c = 0; c < 4; c++) {
      const int row = c * 32 + w * 8 + l8;
      gload16(Ag + (size_t)row * lda + k0 + lc * 8, (char*)As + c * 4096 + w * 1024);
      gload16(Bg + (size_t)row * ldb + k0 + lc * 8, (char*)Bs + c * 4096 + w * 1024);
    }
    __syncthreads();  // compiler drains vmcnt before s_barrier -> staged data visible
    #pragma unroll
    for (int kk = 0; kk < 2; kk++) {
      bf16x8 a[4], b[4];
      #pragma unroll
      for (int i = 0; i < 4; i++) {
        a[i] = *reinterpret_cast<const bf16x8*>(&As[(wm * 64 + i * 16 + ar) * 64 + kk * 32 + ak]);
        b[i] = *reinterpret_cast<const bf16x8*>(&Bs[(wn * 64 + i * 16 + ar) * 64 + kk * 32 + ak]);
      }
      #pragma unroll
      for (int i = 0; i < 4; i++)
        #pragma unroll
        for (int j = 0; j < 4; j++)
          acc[i][j] = __builtin_amdgcn_mfma_f32_16x16x32_bf16(a[i], b[j], acc[i][j], 0, 0, 0);
    }
    __syncthreads();  // all waves done reading before next stage overwrites
  }
}

// ------- Sim = (hc w1) + (hq w2)^T + hc @ (hq*w3)^T + b ; fused row-softmax -> A, mrow ---
__global__ __launch_bounds__(256) void k_sim(const bf16* __restrict__ feats,
                                             const bf16* __restrict__ hqw3,
                                             const float* __restrict__ s1,
                                             const float* __restrict__ s2,
                                             const float* __restrict__ bsim,
                                             bf16* __restrict__ Abf,
                                             float* __restrict__ mrow) {
  __shared__ __align__(16) char smem[128 * 129 * 4];  // gemm uses 32KB; then f32 [128][129]
  __shared__ float invs[128];
  const int b = blockIdx.x, it = blockIdx.y;
  const int m0 = b * LE + it * 128;
  const int t = threadIdx.x;
  f32x4 acc[4][4];
  gemm_core<16>(smem, feats + (size_t)m0 * K4, K4, hqw3 + (size_t)b * LD * DD, DD, acc);

  // scatter Sim tile into LDS with the broadcast adds
  float* simt = (float*)smem;  // [128][129]
  const float bs = bsim[0];
  const int lane = t & 63, w = t >> 6, wm = w >> 1, wn = w & 1;
  #pragma unroll
  for (int i = 0; i < 4; i++)
    #pragma unroll
    for (int r = 0; r < 4; r++) {
      const int ml = wm * 64 + i * 16 + (lane >> 4) * 4 + r;
      const float s1v = s1[m0 + ml] + bs;
      #pragma unroll
      for (int j = 0; j < 4; j++) {
        const int nl = wn * 64 + j * 16 + (lane & 15);
        simt[ml * 129 + nl] = acc[i][j][r] + s1v + s2[b * LD + nl];
      }
    }
  __syncthreads();

  // row softmax over 128 cols: 2 threads per row
  {
    const int row = t >> 1, half = t & 1;
    float* rp = simt + row * 129 + half * 64;
    float m = rp[0];
    #pragma unroll
    for (int k = 1; k < 64; k++) m = fmaxf(m, rp[k]);
    m = fmaxf(m, __shfl_xor(m, 1));
    float s = 0.f;
    #pragma unroll
    for (int k = 0; k < 64; k++) { const float e = __expf(rp[k] - m); rp[k] = e; s += e; }
    s += __shfl_xor(s, 1);
    if (half == 0) { invs[row] = 1.0f / s; mrow[m0 + row] = m; }
  }
  __syncthreads();

  // normalized coalesced bf16 store of A
  #pragma unroll
  for (int it8 = 0; it8 < 8; it8++) {
    const int rr = it8 * 16 + (t >> 4), cc = (t & 15) * 8;
    const float iv = invs[rr];
    bf16x8 o;
    #pragma unroll
    for (int u = 0; u < 8; u++) o[u] = (bf16)(simt[rr * 129 + cc + u] * iv);
    *reinterpret_cast<bf16x8*>(Abf + (size_t)(m0 + rr) * LD + cc) = o;
  }
}

// ---------------- Batt = softmax_i(rowmax) ; hc_bar = Batt-weighted sum of hc -----------
__global__ __launch_bounds__(256) void k_batt(const float* __restrict__ mrow,
                                              const float* __restrict__ hc,
                                              float* __restrict__ hcbar) {
  const int b = blockIdx.x, dc = blockIdx.y, t = threadIdx.x;
  __shared__ float batt[512];
  __shared__ float red[4];
  const int lane = t & 63, w = t >> 6;
  const float m0 = mrow[b * LE + t], m1 = mrow[b * LE + 256 + t];
  float m = fmaxf(m0, m1);
  #pragma unroll
  for (int o = 32; o; o >>= 1) m = fmaxf(m, __shfl_xor(m, o));
  if (lane == 0) red[w] = m;
  __syncthreads();
  m = fmaxf(fmaxf(red[0], red[1]), fmaxf(red[2], red[3]));
  const float e0 = __expf(m0 - m), e1 = __expf(m1 - m);
  float s = e0 + e1;
  #pragma unroll
  for (int o = 32; o; o >>= 1) s += __shfl_xor(s, o);
  __syncthreads();
  if (lane == 0) red[w] = s;
  __syncthreads();
  s = red[0] + red[1] + red[2] + red[3];
  const float inv = 1.0f / s;
  batt[t] = e0 * inv;
  batt[t + 256] = e1 * inv;
  __syncthreads();
  const int d = dc * 256 + t;
  float acc = 0.0f;
  const float* hcb = hc + (size_t)b * LE * DD + d;
  #pragma unroll 8
  for (int i = 0; i < LE; i++) acc += batt[i] * hcb[(size_t)i * DD];
  hcbar[b * DD + d] = acc;
}

// ---------------- hq_hat = A @ hq ; fused feats q1,q2,q3 epilogue (LDS repack) -----------
__global__ __launch_bounds__(256) void k_hqhat(const bf16* __restrict__ Abf,
                                               const bf16* __restrict__ hqT,
                                               const float* __restrict__ hc,
                                               const float* __restrict__ hcbar,
                                               bf16* __restrict__ feats) {
  __shared__ __align__(16) char smem[128 * 136 * 2];  // gemm uses 32KB; then bf16 [128][136]
  const int b = blockIdx.x, it = blockIdx.y, nt = blockIdx.z;
  const int m0 = b * LE + it * 128;
  const int n0 = nt * 128;
  const int t = threadIdx.x;
  f32x4 acc[4][4];
  gemm_core<2>(smem, Abf + (size_t)m0 * LD, LD,
               hqT + (size_t)b * DD * LD + (size_t)n0 * LD, LD, acc);

  // stage hq_hat tile in LDS (pad 136 keeps b128 re-reads 16B-aligned, ~2-way banks)
  bf16* tile = (bf16*)smem;
  const int lane = t & 63, w = t >> 6, wm = w >> 1, wn = w & 1;
  #pragma unroll
  for (int i = 0; i < 4; i++)
    #pragma unroll
    for (int j = 0; j < 4; j++)
      #pragma unroll
      for (int r = 0; r < 4; r++) {
        const int ml = wm * 64 + i * 16 + (lane >> 4) * 4 + r;
        const int nl = wn * 64 + j * 16 + (lane & 15);
        tile[ml * 136 + nl] = (bf16)acc[i][j][r];
      }
  __syncthreads();

  // coalesced pass: 256B-contiguous runs per 16-lane group, 3 quadrants
  const int d = n0 + (t & 15) * 8;
  const float4 hb0 = *reinterpret_cast<const float4*>(hcbar + b * DD + d);
  const float4 hb1 = *reinterpret_cast<const float4*>(hcbar + b * DD + d + 4);
  const float hbv[8] = {hb0.x, hb0.y, hb0.z, hb0.w, hb1.x, hb1.y, hb1.z, hb1.w};
  #pragma unroll
  for (int it8 = 0; it8 < 8; it8++) {
    const int rr = it8 * 16 + (t >> 4);
    const int m = m0 + rr;
    const bf16x8 hv = *reinterpret_cast<const bf16x8*>(&tile[rr * 136 + (t & 15) * 8]);
    const float4 c0 = *reinterpret_cast<const float4*>(hc + (size_t)m * DD + d);
    const float4 c1 = *reinterpret_cast<const float4*>(hc + (size_t)m * DD + d + 4);
    const float hcv[8] = {c0.x, c0.y, c0.z, c0.w, c1.x, c1.y, c1.z, c1.w};
    bf16x8 q2, q3;
    #pragma unroll
    for (int u = 0; u < 8; u++) {
      q2[u] = (bf16)(hcv[u] * (float)hv[u]);
      q3[u] = (bf16)(hcv[u] * hbv[u]);
    }
    bf16* f = feats + (size_t)m * K4;
    *reinterpret_cast<bf16x8*>(f + DD + d) = hv;
    *reinterpret_cast<bf16x8*>(f + 2 * DD + d) = q2;
    *reinterpret_cast<bf16x8*>(f + 3 * DD + d) = q3;
  }
}

// ---------------- out = feats @ W_qv + b_qv  (coalesced float4 epilogue) -----------------
__global__ __launch_bounds__(256) void k_final(const bf16* __restrict__ feats,
                                               const bf16* __restrict__ WT,
                                               const float* __restrict__ bqv,
                                               float* __restrict__ out) {
  __shared__ __align__(16) char smem[64 * 132 * 4];  // gemm uses 32KB; repack f32 [64][132]
  const int mt = blockIdx.x, nt = blockIdx.y;
  const int n0 = nt * 128;
  const int t = threadIdx.x;
  f32x4 acc[4][4];
  gemm_core<64>(smem, feats + (size_t)mt * 128 * K4, K4,
                WT + (size_t)n0 * K4, K4, acc);

  float* tile = (float*)smem;  // [64][132]
  const int lane = t & 63, w = t >> 6, wm = w >> 1, wn = w & 1;
  const int cc = (t & 31) * 4;
  const float4 bq = *reinterpret_cast<const float4*>(bqv + n0 + cc);
  #pragma unroll
  for (int p = 0; p < 2; p++) {
    if (wm == p) {
      #pragma unroll
      for (int i = 0; i < 4; i++)
        #pragma unroll
        for (int j = 0; j < 4; j++)
          #pragma unroll
          for (int r = 0; r < 4; r++) {
            const int ml = i * 16 + (lane >> 4) * 4 + r;            // 0..63
            const int nl = wn * 64 + j * 16 + (lane & 15);
            tile[ml * 132 + nl] = acc[i][j][r];
          }
    }
    __syncthreads();
    #pragma unroll
    for (int itx = 0; itx < 8; itx++) {
      const int rr = itx * 8 + (t >> 5);                            // 0..63
      const f32x4 v = *reinterpret_cast<const f32x4*>(&tile[rr * 132 + cc]);
      float4 o;
      o.x = v[0] + bq.x; o.y = v[1] + bq.y; o.z = v[2] + bq.z; o.w = v[3] + bq.w;
      *reinterpret_cast<float4*>(out + (size_t)(mt * 128 + p * 64 + rr) * DD + n0 + cc) = o;
    }
    __syncthreads();
  }
}

extern "C" void kernel_launch(void* const* d_in, const int* in_sizes, int n_in,
                              void* d_out, int out_size, void* d_ws, size_t ws_size,
                              hipStream_t stream) {
  const float* hc = (const float*)d_in[0];    // (16,512,1024)
  const float* hq = (const float*)d_in[1];    // (16,128,1024)
  const float* wsim = (const float*)d_in[2];  // (3072,)
  const float* bsim = (const float*)d_in[3];  // (1,)
  const float* Wqv = (const float*)d_in[4];   // (4096,1024)
  const float* bqv = (const float*)d_in[5];   // (1024,)
  float* out = (float*)d_out;                 // (16,512,1024)

  char* ws = (char*)d_ws;
  bf16* feats = (bf16*)(ws + OFF_FEATS);
  bf16* hqw3 = (bf16*)(ws + OFF_HQW3);
  bf16* hqT = (bf16*)(ws + OFF_HQT);
  bf16* WT = (bf16*)(ws + OFF_WT);
  bf16* Abf = (bf16*)(ws + OFF_ABF);
  float* s1 = (float*)(ws + OFF_S1);
  float* s2 = (float*)(ws + OFF_S2);
  float* mrow = (float*)(ws + OFF_MROW);
  float* hcbar = (float*)(ws + OFF_HCBAR);

  k_prep<<<MALL + BB * LD, 256, 0, stream>>>(hc, hq, wsim, feats, hqw3, s1, s2);
  // hq (16 x [128 x 1024]) -> hqT (16 x [1024 x 128])
  k_transpose<<<dim3(DD / 64, LD / 64, BB), 256, 0, stream>>>(hq, hqT, LD, DD,
                                                              (long)LD * DD, (long)DD * LD);
  // W_qv (4096 x 1024) -> WT (1024 x 4096)
  k_transpose<<<dim3(DD / 64, K4 / 64, 1), 256, 0, stream>>>(Wqv, WT, K4, DD, 0, 0);
  k_sim<<<dim3(BB, LE / 128), 256, 0, stream>>>(feats, hqw3, s1, s2, bsim, Abf, mrow);
  k_batt<<<dim3(BB, DD / 256), 256, 0, stream>>>(mrow, hc, hcbar);
  k_hqhat<<<dim3(BB, LE / 128, DD / 128), 256, 0, stream>>>(Abf, hqT, hc, hcbar, feats);
  k_final<<<dim3(MALL / 128, DD / 128), 256, 0, stream>>>(feats, WT, bqv, out);
}

// Round 8
// 248.123 us; speedup vs baseline: 1.1225x; 1.1225x over previous
//
#include <hip/hip_runtime.h>

#define DEV __device__ __forceinline__

typedef __bf16 bf16;
typedef __bf16 bf16x4 __attribute__((ext_vector_type(4)));
typedef __bf16 bf16x8 __attribute__((ext_vector_type(8)));
typedef float f32x4 __attribute__((ext_vector_type(4)));

// Problem sizes
constexpr int BB = 16, LE = 512, LD = 128, DD = 1024;
constexpr int MALL = BB * LE;   // 8192 encoder rows total
constexpr int K4 = 4 * DD;      // 4096 feature dim

// ---- workspace layout (bytes) ----
constexpr size_t OFF_FEATS = 0;                                   // bf16 [8192][4096]
constexpr size_t OFF_HQW3  = OFF_FEATS + (size_t)MALL * K4 * 2;   // bf16 [2048][1024]  (hq * w3)
constexpr size_t OFF_HQT   = OFF_HQW3 + (size_t)BB * LD * DD * 2; // bf16 [16][1024][128] (hq^T)
constexpr size_t OFF_WT    = OFF_HQT + (size_t)BB * DD * LD * 2;  // bf16 [1024][4096]  (W_qv^T)
constexpr size_t OFF_ABF   = OFF_WT + (size_t)K4 * DD * 2;        // bf16 [8192][128]   (softmax A)
constexpr size_t OFF_S1    = OFF_ABF + (size_t)MALL * LD * 2;     // f32  [8192]
constexpr size_t OFF_S2    = OFF_S1 + (size_t)MALL * 4;           // f32  [2048]
constexpr size_t OFF_MROW  = OFF_S2 + (size_t)BB * LD * 4;        // f32  [8192]
constexpr size_t OFF_HCBAR = OFF_MROW + (size_t)MALL * 4;         // f32  [16][1024]
// total ~82.1 MB

// async global->LDS, 16B per lane; LDS dest is wave-uniform base (HW adds lane*16)
DEV void gload16(const void* g, void* l) {
  __builtin_amdgcn_global_load_lds(
      (const __attribute__((address_space(1))) void*)g,
      (__attribute__((address_space(3))) void*)l, 16, 0, 0);
}

// ---------------- prep: hc -> feats q0 (bf16) + s1 ; hq -> hq*w3 (bf16) + s2 -------------
__global__ __launch_bounds__(256) void k_prep(const float* __restrict__ hc,
                                              const float* __restrict__ hq,
                                              const float* __restrict__ wsim,
                                              bf16* __restrict__ feats,
                                              bf16* __restrict__ hqw3,
                                              float* __restrict__ s1,
                                              float* __restrict__ s2) {
  const int r = blockIdx.x;
  const int t = threadIdx.x;
  __shared__ float red[4];
  float dot;
  if (r < MALL) {
    const float4 v = reinterpret_cast<const float4*>(hc + (size_t)r * DD)[t];
    const float4 w = reinterpret_cast<const float4*>(wsim)[t];  // w1
    bf16x4 o; o[0] = (bf16)v.x; o[1] = (bf16)v.y; o[2] = (bf16)v.z; o[3] = (bf16)v.w;
    *reinterpret_cast<bf16x4*>(feats + (size_t)r * K4 + t * 4) = o;
    dot = v.x * w.x + v.y * w.y + v.z * w.z + v.w * w.w;
  } else {
    const int rw = r - MALL;  // 0..2047
    const float4 v = reinterpret_cast<const float4*>(hq + (size_t)rw * DD)[t];
    const float4 w2 = reinterpret_cast<const float4*>(wsim + DD)[t];
    const float4 w3 = reinterpret_cast<const float4*>(wsim + 2 * DD)[t];
    bf16x4 o; o[0] = (bf16)(v.x * w3.x); o[1] = (bf16)(v.y * w3.y);
    o[2] = (bf16)(v.z * w3.z); o[3] = (bf16)(v.w * w3.w);
    *reinterpret_cast<bf16x4*>(hqw3 + (size_t)rw * DD + t * 4) = o;
    dot = v.x * w2.x + v.y * w2.y + v.z * w2.z + v.w * w2.w;
  }
  #pragma unroll
  for (int o = 32; o; o >>= 1) dot += __shfl_down(dot, o);
  const int lane = t & 63, w = t >> 6;
  if (lane == 0) red[w] = dot;
  __syncthreads();
  if (t == 0) {
    float s = red[0] + red[1] + red[2] + red[3];
    if (r < MALL) s1[r] = s; else s2[r - MALL] = s;
  }
}

// ---------------- transpose f32 (R x C) -> bf16 (C x R), 64x64 LDS tiles -----------------
__global__ __launch_bounds__(256) void k_transpose(const float* __restrict__ in,
                                                   bf16* __restrict__ out,
                                                   int R, int C, long ibs, long obs) {
  __shared__ float tile[64][68];
  const float* inp = in + (size_t)blockIdx.z * ibs;
  bf16* outp = out + (size_t)blockIdx.z * obs;
  const int r0 = blockIdx.y * 64, c0 = blockIdx.x * 64;
  const int t = threadIdx.x;
  // load full 64x64 tile: 4 iters x 256 threads x float4
  #pragma unroll
  for (int i = 0; i < 4; i++) {
    const int r = i * 16 + (t >> 4), c = (t & 15) << 2;
    const float4 v = *reinterpret_cast<const float4*>(inp + (size_t)(r0 + r) * C + c0 + c);
    tile[r][c] = v.x; tile[r][c + 1] = v.y; tile[r][c + 2] = v.z; tile[r][c + 3] = v.w;
  }
  __syncthreads();
  {
    const int oc = t >> 2;  // out row within tile (source col)
    const int g = t & 3;    // 16-wide group along source rows
    bf16x8 t0, t1;
    #pragma unroll
    for (int i = 0; i < 8; i++) t0[i] = (bf16)tile[g * 16 + i][oc];
    #pragma unroll
    for (int i = 0; i < 8; i++) t1[i] = (bf16)tile[g * 16 + 8 + i][oc];
    bf16* op = outp + (size_t)(c0 + oc) * R + r0 + g * 16;
    *reinterpret_cast<bf16x8*>(op) = t0;
    *reinterpret_cast<bf16x8*>(op + 8) = t1;
  }
}

// ---------------- shared 128x128 MFMA NT GEMM core (m97 structure) -----------------------
// C[m][n] = sum_k A[m][k] * B[n][k] ; lda/ldb in elements; K = KTILES*64
// smem: first 32768 bytes used (As 16KB + Bs 16KB). Ends with __syncthreads().
template <int KTILES>
DEV void gemm_core(char* smem,
                   const bf16* __restrict__ Ag, int lda,
                   const bf16* __restrict__ Bg, int ldb,
                   f32x4 acc[4][4]) {
  bf16* As = (bf16*)smem;
  bf16* Bs = (bf16*)(smem + 16384);
  const int t = threadIdx.x;
  const int lane = t & 63;
  const int w = t >> 6;
  const int wm = w >> 1, wn = w & 1;
  const int l8 = lane >> 3, lc = lane & 7;
  const int ar = lane & 15;
  const int ak = (lane >> 4) * 8;
  const f32x4 zero = {0.f, 0.f, 0.f, 0.f};
  #pragma unroll
  for (int i = 0; i < 4; i++)
    #pragma unroll
    for (int j = 0; j < 4; j++) acc[i][j] = zero;

  for (int kt = 0; kt < KTILES; kt++) {
    const int k0 = kt * 64;
    #pragma unroll
    for (int c = 0; c < 4; c++) {
      const int row = c * 32 + w * 8 + l8;
      gload16(Ag + (size_t)row * lda + k0 + lc * 8, (char*)As + c * 4096 + w * 1024);
      gload16(Bg + (size_t)row * ldb + k0 + lc * 8, (char*)Bs + c * 4096 + w * 1024);
    }
    __syncthreads();  // compiler drains vmcnt before s_barrier -> staged data visible
    #pragma unroll
    for (int kk = 0; kk < 2; kk++) {
      bf16x8 a[4], b[4];
      #pragma unroll
      for (int i = 0; i < 4; i++) {
        a[i] = *reinterpret_cast<const bf16x8*>(&As[(wm * 64 + i * 16 + ar) * 64 + kk * 32 + ak]);
        b[i] = *reinterpret_cast<const bf16x8*>(&Bs[(wn * 64 + i * 16 + ar) * 64 + kk * 32 + ak]);
      }
      #pragma unroll
      for (int i = 0; i < 4; i++)
        #pragma unroll
        for (int j = 0; j < 4; j++)
          acc[i][j] = __builtin_amdgcn_mfma_f32_16x16x32_bf16(a[i], b[j], acc[i][j], 0, 0, 0);
    }
    __syncthreads();  // all waves done reading before next stage overwrites
  }
}

// ------- Sim = (hc w1) + (hq w2)^T + hc @ (hq*w3)^T + b ; fused row-softmax -> A, mrow ---
__global__ __launch_bounds__(256) void k_sim(const bf16* __restrict__ feats,
                                             const bf16* __restrict__ hqw3,
                                             const float* __restrict__ s1,
                                             const float* __restrict__ s2,
                                             const float* __restrict__ bsim,
                                             bf16* __restrict__ Abf,
                                             float* __restrict__ mrow) {
  __shared__ __align__(16) char smem[128 * 129 * 4];  // gemm uses 32KB; then f32 [128][129]
  __shared__ float invs[128];
  const int b = blockIdx.x, it = blockIdx.y;
  const int m0 = b * LE + it * 128;
  const int t = threadIdx.x;
  f32x4 acc[4][4];
  gemm_core<16>(smem, feats + (size_t)m0 * K4, K4, hqw3 + (size_t)b * LD * DD, DD, acc);

  // scatter Sim tile into LDS with the broadcast adds
  float* simt = (float*)smem;  // [128][129]
  const float bs = bsim[0];
  const int lane = t & 63, w = t >> 6, wm = w >> 1, wn = w & 1;
  #pragma unroll
  for (int i = 0; i < 4; i++)
    #pragma unroll
    for (int r = 0; r < 4; r++) {
      const int ml = wm * 64 + i * 16 + (lane >> 4) * 4 + r;
      const float s1v = s1[m0 + ml] + bs;
      #pragma unroll
      for (int j = 0; j < 4; j++) {
        const int nl = wn * 64 + j * 16 + (lane & 15);
        simt[ml * 129 + nl] = acc[i][j][r] + s1v + s2[b * LD + nl];
      }
    }
  __syncthreads();

  // row softmax over 128 cols: 2 threads per row
  {
    const int row = t >> 1, half = t & 1;
    float* rp = simt + row * 129 + half * 64;
    float m = rp[0];
    #pragma unroll
    for (int k = 1; k < 64; k++) m = fmaxf(m, rp[k]);
    m = fmaxf(m, __shfl_xor(m, 1));
    float s = 0.f;
    #pragma unroll
    for (int k = 0; k < 64; k++) { const float e = __expf(rp[k] - m); rp[k] = e; s += e; }
    s += __shfl_xor(s, 1);
    if (half == 0) { invs[row] = 1.0f / s; mrow[m0 + row] = m; }
  }
  __syncthreads();

  // normalized coalesced bf16 store of A
  #pragma unroll
  for (int it8 = 0; it8 < 8; it8++) {
    const int rr = it8 * 16 + (t >> 4), cc = (t & 15) * 8;
    const float iv = invs[rr];
    bf16x8 o;
    #pragma unroll
    for (int u = 0; u < 8; u++) o[u] = (bf16)(simt[rr * 129 + cc + u] * iv);
    *reinterpret_cast<bf16x8*>(Abf + (size_t)(m0 + rr) * LD + cc) = o;
  }
}

// ---------------- Batt = softmax_i(rowmax) ; hc_bar = Batt-weighted sum of hc -----------
__global__ __launch_bounds__(256) void k_batt(const float* __restrict__ mrow,
                                              const float* __restrict__ hc,
                                              float* __restrict__ hcbar) {
  const int b = blockIdx.x, dc = blockIdx.y, t = threadIdx.x;
  __shared__ float batt[512];
  __shared__ float red[4];
  const int lane = t & 63, w = t >> 6;
  const float m0 = mrow[b * LE + t], m1 = mrow[b * LE + 256 + t];
  float m = fmaxf(m0, m1);
  #pragma unroll
  for (int o = 32; o; o >>= 1) m = fmaxf(m, __shfl_xor(m, o));
  if (lane == 0) red[w] = m;
  __syncthreads();
  m = fmaxf(fmaxf(red[0], red[1]), fmaxf(red[2], red[3]));
  const float e0 = __expf(m0 - m), e1 = __expf(m1 - m);
  float s = e0 + e1;
  #pragma unroll
  for (int o = 32; o; o >>= 1) s += __shfl_xor(s, o);
  __syncthreads();
  if (lane == 0) red[w] = s;
  __syncthreads();
  s = red[0] + red[1] + red[2] + red[3];
  const float inv = 1.0f / s;
  batt[t] = e0 * inv;
  batt[t + 256] = e1 * inv;
  __syncthreads();
  const int d = dc * 256 + t;
  float acc = 0.0f;
  const float* hcb = hc + (size_t)b * LE * DD + d;
  #pragma unroll 8
  for (int i = 0; i < LE; i++) acc += batt[i] * hcb[(size_t)i * DD];
  hcbar[b * DD + d] = acc;
}

// ---------------- hq_hat = A @ hq ; fused feats q1,q2,q3 epilogue (LDS repack) -----------
__global__ __launch_bounds__(256) void k_hqhat(const bf16* __restrict__ Abf,
                                               const bf16* __restrict__ hqT,
                                               const float* __restrict__ hc,
                                               const float* __restrict__ hcbar,
                                               bf16* __restrict__ feats) {
  __shared__ __align__(16) char smem[128 * 136 * 2];  // gemm uses 32KB; then bf16 [128][136]
  const int b = blockIdx.x, it = blockIdx.y, nt = blockIdx.z;
  const int m0 = b * LE + it * 128;
  const int n0 = nt * 128;
  const int t = threadIdx.x;
  f32x4 acc[4][4];
  gemm_core<2>(smem, Abf + (size_t)m0 * LD, LD,
               hqT + (size_t)b * DD * LD + (size_t)n0 * LD, LD, acc);

  // stage hq_hat tile in LDS (pad 136 keeps b128 re-reads 16B-aligned, ~2-way banks)
  bf16* tile = (bf16*)smem;
  const int lane = t & 63, w = t >> 6, wm = w >> 1, wn = w & 1;
  #pragma unroll
  for (int i = 0; i < 4; i++)
    #pragma unroll
    for (int j = 0; j < 4; j++)
      #pragma unroll
      for (int r = 0; r < 4; r++) {
        const int ml = wm * 64 + i * 16 + (lane >> 4) * 4 + r;
        const int nl = wn * 64 + j * 16 + (lane & 15);
        tile[ml * 136 + nl] = (bf16)acc[i][j][r];
      }
  __syncthreads();

  // coalesced pass: 256B-contiguous runs per 16-lane group, 3 quadrants
  const int d = n0 + (t & 15) * 8;
  const float4 hb0 = *reinterpret_cast<const float4*>(hcbar + b * DD + d);
  const float4 hb1 = *reinterpret_cast<const float4*>(hcbar + b * DD + d + 4);
  const float hbv[8] = {hb0.x, hb0.y, hb0.z, hb0.w, hb1.x, hb1.y, hb1.z, hb1.w};
  #pragma unroll
  for (int it8 = 0; it8 < 8; it8++) {
    const int rr = it8 * 16 + (t >> 4);
    const int m = m0 + rr;
    const bf16x8 hv = *reinterpret_cast<const bf16x8*>(&tile[rr * 136 + (t & 15) * 8]);
    const float4 c0 = *reinterpret_cast<const float4*>(hc + (size_t)m * DD + d);
    const float4 c1 = *reinterpret_cast<const float4*>(hc + (size_t)m * DD + d + 4);
    const float hcv[8] = {c0.x, c0.y, c0.z, c0.w, c1.x, c1.y, c1.z, c1.w};
    bf16x8 q2, q3;
    #pragma unroll
    for (int u = 0; u < 8; u++) {
      q2[u] = (bf16)(hcv[u] * (float)hv[u]);
      q3[u] = (bf16)(hcv[u] * hbv[u]);
    }
    bf16* f = feats + (size_t)m * K4;
    *reinterpret_cast<bf16x8*>(f + DD + d) = hv;
    *reinterpret_cast<bf16x8*>(f + 2 * DD + d) = q2;
    *reinterpret_cast<bf16x8*>(f + 3 * DD + d) = q3;
  }
}

// ======== out = feats @ W_qv + b_qv — phased pipeline ====================================
// BM=256, BN=128, BK=64, 512 thr (8 waves, 4M x 2N, per-wave 64x64).
// 3 LDS buffers (48KB each), prefetch 2 K-tiles ahead, counted vmcnt(6) per tile.
// T2 swizzle: global source chunk pre-permuted (lc^l8 within 128B row), LDS dest linear,
// ds_read applies inverse XOR -> uniform bank spread (rule #21 both-sides involution).
__global__ __launch_bounds__(512, 2) void k_final2(const bf16* __restrict__ feats,
                                                   const bf16* __restrict__ WT,
                                                   const float* __restrict__ bqv,
                                                   float* __restrict__ out) {
  __shared__ __align__(16) char smem[3 * 49152];  // 144 KB
  const int mt = blockIdx.x, nt = blockIdx.y;
  const int t = threadIdx.x;
  const int lane = t & 63, w = t >> 6;            // 8 waves
  const int wm = w >> 1, wn = w & 1;              // 4M x 2N
  const int l8 = lane >> 3, lc = lane & 7;
  const int ar = lane & 15;
  const int cg = lane >> 4;                       // 0..3
  const int a7 = lane & 7;
  const int arow = w * 8 + l8;                    // staging row within 64-row chunk
  const int schunk = (lc ^ l8) * 8;               // pre-swizzled source chunk (elements)
  const int w8 = w * 8;

  const bf16* Ag = feats + (size_t)mt * 256 * K4;
  const bf16* Bg = WT + (size_t)nt * 128 * K4;

  f32x4 acc[4][4];
  const f32x4 zero = {0.f, 0.f, 0.f, 0.f};
  #pragma unroll
  for (int i = 0; i < 4; i++)
    #pragma unroll
    for (int j = 0; j < 4; j++) acc[i][j] = zero;

  // stage one tile's A-chunk c (0..3) / B-chunk c (0..1) at k-offset k0 into buffer base
  #define STAGE_A(base, c, k0) \
    gload16(Ag + (size_t)((c) * 64 + arow) * K4 + (k0) + schunk, (base) + ((c) * 64 + w8) * 128)
  #define STAGE_B(base, c, k0) \
    gload16(Bg + (size_t)((c) * 64 + arow) * K4 + (k0) + schunk, (base) + 32768 + ((c) * 64 + w8) * 128)

  // frag reads with inverse swizzle
  #define LDA(base, i, kk) \
    (*(const bf16x8*)((base) + (wm * 64 + (i) * 16 + ar) * 128 + (((kk) * 4 + cg) ^ a7) * 16))
  #define LDB(base, j, kk) \
    (*(const bf16x8*)((base) + 32768 + (wn * 64 + (j) * 16 + ar) * 128 + (((kk) * 4 + cg) ^ a7) * 16))

  // prologue: stage tiles 0 (buf0) and 1 (buf1)
  {
    char* b0 = smem;
    STAGE_A(b0, 0, 0); STAGE_A(b0, 1, 0); STAGE_A(b0, 2, 0); STAGE_A(b0, 3, 0);
    STAGE_B(b0, 0, 0); STAGE_B(b0, 1, 0);
    char* b1 = smem + 49152;
    STAGE_A(b1, 0, 64); STAGE_A(b1, 1, 64); STAGE_A(b1, 2, 64); STAGE_A(b1, 3, 64);
    STAGE_B(b1, 0, 64); STAGE_B(b1, 1, 64);
  }
  asm volatile("s_waitcnt vmcnt(6)" ::: "memory");  // tile 0 landed
  __builtin_amdgcn_s_barrier();

  int rd = 0, st = 2;
  for (int kt = 0; kt < 64; kt++) {
    char* bA = smem + rd * 49152;
    char* sA = smem + st * 49152;
    const int k2 = (kt + 2) * 64;
    const bool do_stage = (kt + 2) < 64;
    bf16x8 a[4], b[4];

    // ---- phase 0 (kk=0) ----
    #pragma unroll
    for (int i = 0; i < 4; i++) a[i] = LDA(bA, i, 0);
    #pragma unroll
    for (int j = 0; j < 4; j++) b[j] = LDB(bA, j, 0);
    if (do_stage) { STAGE_A(sA, 0, k2); STAGE_A(sA, 1, k2); STAGE_B(sA, 0, k2); }
    __builtin_amdgcn_s_barrier();
    asm volatile("s_waitcnt lgkmcnt(0)" ::: "memory");
    __builtin_amdgcn_sched_barrier(0);
    __builtin_amdgcn_s_setprio(1);
    #pragma unroll
    for (int i = 0; i < 4; i++)
      #pragma unroll
      for (int j = 0; j < 4; j++)
        acc[i][j] = __builtin_amdgcn_mfma_f32_16x16x32_bf16(a[i], b[j], acc[i][j], 0, 0, 0);
    __builtin_amdgcn_s_setprio(0);
    __builtin_amdgcn_s_barrier();

    // ---- phase 1 (kk=1) ----
    #pragma unroll
    for (int i = 0; i < 4; i++) a[i] = LDA(bA, i, 1);
    #pragma unroll
    for (int j = 0; j < 4; j++) b[j] = LDB(bA, j, 1);
    if (do_stage) { STAGE_A(sA, 2, k2); STAGE_A(sA, 3, k2); STAGE_B(sA, 1, k2); }
    __builtin_amdgcn_s_barrier();
    asm volatile("s_waitcnt lgkmcnt(0)" ::: "memory");
    __builtin_amdgcn_sched_barrier(0);
    __builtin_amdgcn_s_setprio(1);
    #pragma unroll
    for (int i = 0; i < 4; i++)
      #pragma unroll
      for (int j = 0; j < 4; j++)
        acc[i][j] = __builtin_amdgcn_mfma_f32_16x16x32_bf16(a[i], b[j], acc[i][j], 0, 0, 0);
    __builtin_amdgcn_s_setprio(0);
    // tile boundary: next tile's loads were issued a full tile ago -> counted wait ~free
    if (do_stage) asm volatile("s_waitcnt vmcnt(6)" ::: "memory");
    else          asm volatile("s_waitcnt vmcnt(0)" ::: "memory");
    __builtin_amdgcn_s_barrier();

    rd = (rd == 2) ? 0 : rd + 1;
    st = (st == 2) ? 0 : st + 1;
  }
  #undef STAGE_A
  #undef STAGE_B
  #undef LDA
  #undef LDB

  // keep the K-loop's counted vmcnt semantics sealed: no VMEM op may be scheduled
  // above this point (e.g. the bqv load below) or vmcnt(6) would miscount.
  __builtin_amdgcn_sched_barrier(0);

  // epilogue: LDS repack -> coalesced float4 stores (4 passes of 64 rows)
  float* tile = (float*)smem;  // [64][132] = 33792 B
  const int cc = (t & 31) * 4;
  const float4 bq = *reinterpret_cast<const float4*>(bqv + nt * 128 + cc);
  __syncthreads();
  #pragma unroll
  for (int p = 0; p < 4; p++) {
    if (wm == p) {
      #pragma unroll
      for (int i = 0; i < 4; i++)
        #pragma unroll
        for (int j = 0; j < 4; j++)
          #pragma unroll
          for (int r = 0; r < 4; r++) {
            const int ml = i * 16 + (lane >> 4) * 4 + r;          // 0..63
            const int nl = wn * 64 + j * 16 + (lane & 15);
            tile[ml * 132 + nl] = acc[i][j][r];
          }
    }
    __syncthreads();
    #pragma unroll
    for (int itx = 0; itx < 4; itx++) {
      const int rr = itx * 16 + (t >> 5);                          // 0..63
      const f32x4 v = *reinterpret_cast<const f32x4*>(&tile[rr * 132 + cc]);
      float4 o;
      o.x = v[0] + bq.x; o.y = v[1] + bq.y; o.z = v[2] + bq.z; o.w = v[3] + bq.w;
      *reinterpret_cast<float4*>(out + (size_t)(mt * 256 + p * 64 + rr) * DD + nt * 128 + cc) = o;
    }
    __syncthreads();
  }
}

extern "C" void kernel_launch(void* const* d_in, const int* in_sizes, int n_in,
                              void* d_out, int out_size, void* d_ws, size_t ws_size,
                              hipStream_t stream) {
  const float* hc = (const float*)d_in[0];    // (16,512,1024)
  const float* hq = (const float*)d_in[1];    // (16,128,1024)
  const float* wsim = (const float*)d_in[2];  // (3072,)
  const float* bsim = (const float*)d_in[3];  // (1,)
  const float* Wqv = (const float*)d_in[4];   // (4096,1024)
  const float* bqv = (const float*)d_in[5];   // (1024,)
  float* out = (float*)d_out;                 // (16,512,1024)

  char* ws = (char*)d_ws;
  bf16* feats = (bf16*)(ws + OFF_FEATS);
  bf16* hqw3 = (bf16*)(ws + OFF_HQW3);
  bf16* hqT = (bf16*)(ws + OFF_HQT);
  bf16* WT = (bf16*)(ws + OFF_WT);
  bf16* Abf = (bf16*)(ws + OFF_ABF);
  float* s1 = (float*)(ws + OFF_S1);
  float* s2 = (float*)(ws + OFF_S2);
  float* mrow = (float*)(ws + OFF_MROW);
  float* hcbar = (float*)(ws + OFF_HCBAR);

  k_prep<<<MALL + BB * LD, 256, 0, stream>>>(hc, hq, wsim, feats, hqw3, s1, s2);
  // hq (16 x [128 x 1024]) -> hqT (16 x [1024 x 128])
  k_transpose<<<dim3(DD / 64, LD / 64, BB), 256, 0, stream>>>(hq, hqT, LD, DD,
                                                              (long)LD * DD, (long)DD * LD);
  // W_qv (4096 x 1024) -> WT (1024 x 4096)
  k_transpose<<<dim3(DD / 64, K4 / 64, 1), 256, 0, stream>>>(Wqv, WT, K4, DD, 0, 0);
  k_sim<<<dim3(BB, LE / 128), 256, 0, stream>>>(feats, hqw3, s1, s2, bsim, Abf, mrow);
  k_batt<<<dim3(BB, DD / 256), 256, 0, stream>>>(mrow, hc, hcbar);
  k_hqhat<<<dim3(BB, LE / 128, DD / 128), 256, 0, stream>>>(Abf, hqT, hc, hcbar, feats);
  k_final2<<<dim3(MALL / 256, DD / 128), 512, 0, stream>>>(feats, WT, bqv, out);
}

// Round 11
// 242.961 us; speedup vs baseline: 1.1464x; 1.0212x over previous
//
#include <hip/hip_runtime.h>

#define DEV __device__ __forceinline__

typedef __bf16 bf16;
typedef __bf16 bf16x4 __attribute__((ext_vector_type(4)));
typedef __bf16 bf16x8 __attribute__((ext_vector_type(8)));
typedef float f32x4 __attribute__((ext_vector_type(4)));

// Problem sizes
constexpr int BB = 16, LE = 512, LD = 128, DD = 1024;
constexpr int MALL = BB * LE;   // 8192 encoder rows total
constexpr int K4 = 4 * DD;      // 4096 feature dim

// ---- workspace layout (bytes) ----
constexpr size_t OFF_FEATS = 0;                                   // bf16 [8192][4096]
constexpr size_t OFF_HQW3  = OFF_FEATS + (size_t)MALL * K4 * 2;   // bf16 [2048][1024]  (hq * w3)
constexpr size_t OFF_HQT   = OFF_HQW3 + (size_t)BB * LD * DD * 2; // bf16 [16][1024][128] (hq^T)
constexpr size_t OFF_WT    = OFF_HQT + (size_t)BB * DD * LD * 2;  // bf16 [1024][4096]  (W_qv^T)
constexpr size_t OFF_ABF   = OFF_WT + (size_t)K4 * DD * 2;        // bf16 [8192][128]   (softmax A)
constexpr size_t OFF_S1    = OFF_ABF + (size_t)MALL * LD * 2;     // f32  [8192]
constexpr size_t OFF_S2    = OFF_S1 + (size_t)MALL * 4;           // f32  [2048]
constexpr size_t OFF_MROW  = OFF_S2 + (size_t)BB * LD * 4;        // f32  [8192]
constexpr size_t OFF_HCBAR = OFF_MROW + (size_t)MALL * 4;         // f32  [16][1024]
// total ~82.1 MB

// async global->LDS, 16B per lane; LDS dest is wave-uniform base (HW adds lane*16)
DEV void gload16(const void* g, void* l) {
  __builtin_amdgcn_global_load_lds(
      (const __attribute__((address_space(1))) void*)g,
      (__attribute__((address_space(3))) void*)l, 16, 0, 0);
}

// ---------------- prep: hc -> feats q0 (bf16) + s1 ; hq -> hq*w3 (bf16) + s2 -------------
__global__ __launch_bounds__(256) void k_prep(const float* __restrict__ hc,
                                              const float* __restrict__ hq,
                                              const float* __restrict__ wsim,
                                              bf16* __restrict__ feats,
                                              bf16* __restrict__ hqw3,
                                              float* __restrict__ s1,
                                              float* __restrict__ s2) {
  const int r = blockIdx.x;
  const int t = threadIdx.x;
  __shared__ float red[4];
  float dot;
  if (r < MALL) {
    const float4 v = reinterpret_cast<const float4*>(hc + (size_t)r * DD)[t];
    const float4 w = reinterpret_cast<const float4*>(wsim)[t];  // w1
    bf16x4 o; o[0] = (bf16)v.x; o[1] = (bf16)v.y; o[2] = (bf16)v.z; o[3] = (bf16)v.w;
    *reinterpret_cast<bf16x4*>(feats + (size_t)r * K4 + t * 4) = o;
    dot = v.x * w.x + v.y * w.y + v.z * w.z + v.w * w.w;
  } else {
    const int rw = r - MALL;  // 0..2047
    const float4 v = reinterpret_cast<const float4*>(hq + (size_t)rw * DD)[t];
    const float4 w2 = reinterpret_cast<const float4*>(wsim + DD)[t];
    const float4 w3 = reinterpret_cast<const float4*>(wsim + 2 * DD)[t];
    bf16x4 o; o[0] = (bf16)(v.x * w3.x); o[1] = (bf16)(v.y * w3.y);
    o[2] = (bf16)(v.z * w3.z); o[3] = (bf16)(v.w * w3.w);
    *reinterpret_cast<bf16x4*>(hqw3 + (size_t)rw * DD + t * 4) = o;
    dot = v.x * w2.x + v.y * w2.y + v.z * w2.z + v.w * w2.w;
  }
  #pragma unroll
  for (int o = 32; o; o >>= 1) dot += __shfl_down(dot, o);
  const int lane = t & 63, w = t >> 6;
  if (lane == 0) red[w] = dot;
  __syncthreads();
  if (t == 0) {
    float s = red[0] + red[1] + red[2] + red[3];
    if (r < MALL) s1[r] = s; else s2[r - MALL] = s;
  }
}

// ---------------- transpose f32 (R x C) -> bf16 (C x R), 64x64 LDS tiles -----------------
__global__ __launch_bounds__(256) void k_transpose(const float* __restrict__ in,
                                                   bf16* __restrict__ out,
                                                   int R, int C, long ibs, long obs) {
  __shared__ float tile[64][68];
  const float* inp = in + (size_t)blockIdx.z * ibs;
  bf16* outp = out + (size_t)blockIdx.z * obs;
  const int r0 = blockIdx.y * 64, c0 = blockIdx.x * 64;
  const int t = threadIdx.x;
  // load full 64x64 tile: 4 iters x 256 threads x float4
  #pragma unroll
  for (int i = 0; i < 4; i++) {
    const int r = i * 16 + (t >> 4), c = (t & 15) << 2;
    const float4 v = *reinterpret_cast<const float4*>(inp + (size_t)(r0 + r) * C + c0 + c);
    tile[r][c] = v.x; tile[r][c + 1] = v.y; tile[r][c + 2] = v.z; tile[r][c + 3] = v.w;
  }
  __syncthreads();
  {
    const int oc = t >> 2;  // out row within tile (source col)
    const int g = t & 3;    // 16-wide group along source rows
    bf16x8 t0, t1;
    #pragma unroll
    for (int i = 0; i < 8; i++) t0[i] = (bf16)tile[g * 16 + i][oc];
    #pragma unroll
    for (int i = 0; i < 8; i++) t1[i] = (bf16)tile[g * 16 + 8 + i][oc];
    bf16* op = outp + (size_t)(c0 + oc) * R + r0 + g * 16;
    *reinterpret_cast<bf16x8*>(op) = t0;
    *reinterpret_cast<bf16x8*>(op + 8) = t1;
  }
}

// ---------------- shared 128x128 MFMA NT GEMM core (m97 structure) -----------------------
// C[m][n] = sum_k A[m][k] * B[n][k] ; lda/ldb in elements; K = KTILES*64
// smem: first 32768 bytes used (As 16KB + Bs 16KB). Ends with __syncthreads().
template <int KTILES>
DEV void gemm_core(char* smem,
                   const bf16* __restrict__ Ag, int lda,
                   const bf16* __restrict__ Bg, int ldb,
                   f32x4 acc[4][4]) {
  bf16* As = (bf16*)smem;
  bf16* Bs = (bf16*)(smem + 16384);
  const int t = threadIdx.x;
  const int lane = t & 63;
  const int w = t >> 6;
  const int wm = w >> 1, wn = w & 1;
  const int l8 = lane >> 3, lc = lane & 7;
  const int ar = lane & 15;
  const int ak = (lane >> 4) * 8;
  const f32x4 zero = {0.f, 0.f, 0.f, 0.f};
  #pragma unroll
  for (int i = 0; i < 4; i++)
    #pragma unroll
    for (int j = 0; j < 4; j++) acc[i][j] = zero;

  for (int kt = 0; kt < KTILES; kt++) {
    const int k0 = kt * 64;
    #pragma unroll
    for (int c = 0; c < 4; c++) {
      const int row = c * 32 + w * 8 + l8;
      gload16(Ag + (size_t)row * lda + k0 + lc * 8, (char*)As + c * 4096 + w * 1024);
      gload16(Bg + (size_t)row * ldb + k0 + lc * 8, (char*)Bs + c * 4096 + w * 1024);
    }
    __syncthreads();  // compiler drains vmcnt before s_barrier -> staged data visible
    #pragma unroll
    for (int kk = 0; kk < 2; kk++) {
      bf16x8 a[4], b[4];
      #pragma unroll
      for (int i = 0; i < 4; i++) {
        a[i] = *reinterpret_cast<const bf16x8*>(&As[(wm * 64 + i * 16 + ar) * 64 + kk * 32 + ak]);
        b[i] = *reinterpret_cast<const bf16x8*>(&Bs[(wn * 64 + i * 16 + ar) * 64 + kk * 32 + ak]);
      }
      #pragma unroll
      for (int i = 0; i < 4; i++)
        #pragma unroll
        for (int j = 0; j < 4; j++)
          acc[i][j] = __builtin_amdgcn_mfma_f32_16x16x32_bf16(a[i], b[j], acc[i][j], 0, 0, 0);
    }
    __syncthreads();  // all waves done reading before next stage overwrites
  }
}

// ------- Sim = (hc w1) + (hq w2)^T + hc @ (hq*w3)^T + b ; fused row-softmax -> A, mrow ---
__global__ __launch_bounds__(256) void k_sim(const bf16* __restrict__ feats,
                                             const bf16* __restrict__ hqw3,
                                             const float* __restrict__ s1,
                                             const float* __restrict__ s2,
                                             const float* __restrict__ bsim,
                                             bf16* __restrict__ Abf,
                                             float* __restrict__ mrow) {
  __shared__ __align__(16) char smem[128 * 129 * 4];  // gemm uses 32KB; then f32 [128][129]
  __shared__ float invs[128];
  const int b = blockIdx.x, it = blockIdx.y;
  const int m0 = b * LE + it * 128;
  const int t = threadIdx.x;
  f32x4 acc[4][4];
  gemm_core<16>(smem, feats + (size_t)m0 * K4, K4, hqw3 + (size_t)b * LD * DD, DD, acc);

  // scatter Sim tile into LDS with the broadcast adds
  float* simt = (float*)smem;  // [128][129]
  const float bs = bsim[0];
  const int lane = t & 63, w = t >> 6, wm = w >> 1, wn = w & 1;
  #pragma unroll
  for (int i = 0; i < 4; i++)
    #pragma unroll
    for (int r = 0; r < 4; r++) {
      const int ml = wm * 64 + i * 16 + (lane >> 4) * 4 + r;
      const float s1v = s1[m0 + ml] + bs;
      #pragma unroll
      for (int j = 0; j < 4; j++) {
        const int nl = wn * 64 + j * 16 + (lane & 15);
        simt[ml * 129 + nl] = acc[i][j][r] + s1v + s2[b * LD + nl];
      }
    }
  __syncthreads();

  // row softmax over 128 cols: 2 threads per row
  {
    const int row = t >> 1, half = t & 1;
    float* rp = simt + row * 129 + half * 64;
    float m = rp[0];
    #pragma unroll
    for (int k = 1; k < 64; k++) m = fmaxf(m, rp[k]);
    m = fmaxf(m, __shfl_xor(m, 1));
    float s = 0.f;
    #pragma unroll
    for (int k = 0; k < 64; k++) { const float e = __expf(rp[k] - m); rp[k] = e; s += e; }
    s += __shfl_xor(s, 1);
    if (half == 0) { invs[row] = 1.0f / s; mrow[m0 + row] = m; }
  }
  __syncthreads();

  // normalized coalesced bf16 store of A
  #pragma unroll
  for (int it8 = 0; it8 < 8; it8++) {
    const int rr = it8 * 16 + (t >> 4), cc = (t & 15) * 8;
    const float iv = invs[rr];
    bf16x8 o;
    #pragma unroll
    for (int u = 0; u < 8; u++) o[u] = (bf16)(simt[rr * 129 + cc + u] * iv);
    *reinterpret_cast<bf16x8*>(Abf + (size_t)(m0 + rr) * LD + cc) = o;
  }
}

// ---------------- Batt = softmax_i(rowmax) ; hc_bar = Batt-weighted sum of hc -----------
__global__ __launch_bounds__(256) void k_batt(const float* __restrict__ mrow,
                                              const float* __restrict__ hc,
                                              float* __restrict__ hcbar) {
  const int b = blockIdx.x, dc = blockIdx.y, t = threadIdx.x;
  __shared__ float batt[512];
  __shared__ float red[4];
  const int lane = t & 63, w = t >> 6;
  const float m0 = mrow[b * LE + t], m1 = mrow[b * LE + 256 + t];
  float m = fmaxf(m0, m1);
  #pragma unroll
  for (int o = 32; o; o >>= 1) m = fmaxf(m, __shfl_xor(m, o));
  if (lane == 0) red[w] = m;
  __syncthreads();
  m = fmaxf(fmaxf(red[0], red[1]), fmaxf(red[2], red[3]));
  const float e0 = __expf(m0 - m), e1 = __expf(m1 - m);
  float s = e0 + e1;
  #pragma unroll
  for (int o = 32; o; o >>= 1) s += __shfl_xor(s, o);
  __syncthreads();
  if (lane == 0) red[w] = s;
  __syncthreads();
  s = red[0] + red[1] + red[2] + red[3];
  const float inv = 1.0f / s;
  batt[t] = e0 * inv;
  batt[t + 256] = e1 * inv;
  __syncthreads();
  const int d = dc * 256 + t;
  float acc = 0.0f;
  const float* hcb = hc + (size_t)b * LE * DD + d;
  #pragma unroll 8
  for (int i = 0; i < LE; i++) acc += batt[i] * hcb[(size_t)i * DD];
  hcbar[b * DD + d] = acc;
}

// ---------------- hq_hat = A @ hq ; fused feats q1,q2,q3 epilogue (LDS repack) -----------
__global__ __launch_bounds__(256) void k_hqhat(const bf16* __restrict__ Abf,
                                               const bf16* __restrict__ hqT,
                                               const float* __restrict__ hc,
                                               const float* __restrict__ hcbar,
                                               bf16* __restrict__ feats) {
  __shared__ __align__(16) char smem[128 * 136 * 2];  // gemm uses 32KB; then bf16 [128][136]
  const int b = blockIdx.x, it = blockIdx.y, nt = blockIdx.z;
  const int m0 = b * LE + it * 128;
  const int n0 = nt * 128;
  const int t = threadIdx.x;
  f32x4 acc[4][4];
  gemm_core<2>(smem, Abf + (size_t)m0 * LD, LD,
               hqT + (size_t)b * DD * LD + (size_t)n0 * LD, LD, acc);

  // stage hq_hat tile in LDS (pad 136 keeps b128 re-reads 16B-aligned, ~2-way banks)
  bf16* tile = (bf16*)smem;
  const int lane = t & 63, w = t >> 6, wm = w >> 1, wn = w & 1;
  #pragma unroll
  for (int i = 0; i < 4; i++)
    #pragma unroll
    for (int j = 0; j < 4; j++)
      #pragma unroll
      for (int r = 0; r < 4; r++) {
        const int ml = wm * 64 + i * 16 + (lane >> 4) * 4 + r;
        const int nl = wn * 64 + j * 16 + (lane & 15);
        tile[ml * 136 + nl] = (bf16)acc[i][j][r];
      }
  __syncthreads();

  // coalesced pass: 256B-contiguous runs per 16-lane group, 3 quadrants
  const int d = n0 + (t & 15) * 8;
  const float4 hb0 = *reinterpret_cast<const float4*>(hcbar + b * DD + d);
  const float4 hb1 = *reinterpret_cast<const float4*>(hcbar + b * DD + d + 4);
  const float hbv[8] = {hb0.x, hb0.y, hb0.z, hb0.w, hb1.x, hb1.y, hb1.z, hb1.w};
  #pragma unroll
  for (int it8 = 0; it8 < 8; it8++) {
    const int rr = it8 * 16 + (t >> 4);
    const int m = m0 + rr;
    const bf16x8 hv = *reinterpret_cast<const bf16x8*>(&tile[rr * 136 + (t & 15) * 8]);
    const float4 c0 = *reinterpret_cast<const float4*>(hc + (size_t)m * DD + d);
    const float4 c1 = *reinterpret_cast<const float4*>(hc + (size_t)m * DD + d + 4);
    const float hcv[8] = {c0.x, c0.y, c0.z, c0.w, c1.x, c1.y, c1.z, c1.w};
    bf16x8 q2, q3;
    #pragma unroll
    for (int u = 0; u < 8; u++) {
      q2[u] = (bf16)(hcv[u] * (float)hv[u]);
      q3[u] = (bf16)(hcv[u] * hbv[u]);
    }
    bf16* f = feats + (size_t)m * K4;
    *reinterpret_cast<bf16x8*>(f + DD + d) = hv;
    *reinterpret_cast<bf16x8*>(f + 2 * DD + d) = q2;
    *reinterpret_cast<bf16x8*>(f + 3 * DD + d) = q3;
  }
}

// ======== out = feats @ W_qv + b_qv — phased pipeline, 1 barrier per K-tile ==============
// BM=256, BN=128, BK=64, 512 thr (8 waves, 4M x 2N, per-wave 64x64).
// 3 LDS buffers (48KB each), prefetch 2 K-tiles ahead, counted vmcnt(6) per tile.
// R8 profile: bank-conflict 0 but MfmaUtil 36% -> LDS-issue + barrier-serialization bound
// (6 barriers/K-tile). This version: all 16 ds_reads + 6 stages issue up front, compiler
// interleaves MFMA via fine-grained lgkmcnt, ONE vmcnt+barrier per K-tile.
// Safety: reads of buf[rd] are register-consumed before tile-end barrier (lgkmcnt before
// last MFMA); stage at kt targets buf[(kt+2)%3], last read at kt-1 behind its barrier;
// per-wave vmcnt(6) retires own 6 stages of tile kt+1, barrier publishes all waves'.
__global__ __launch_bounds__(512, 2) void k_final2(const bf16* __restrict__ feats,
                                                   const bf16* __restrict__ WT,
                                                   const float* __restrict__ bqv,
                                                   float* __restrict__ out) {
  __shared__ __align__(16) char smem[3 * 49152];  // 144 KB
  const int mt = blockIdx.x, nt = blockIdx.y;
  const int t = threadIdx.x;
  const int lane = t & 63, w = t >> 6;            // 8 waves
  const int wm = w >> 1, wn = w & 1;              // 4M x 2N
  const int l8 = lane >> 3, lc = lane & 7;
  const int ar = lane & 15;
  const int cg = lane >> 4;                       // 0..3
  const int a7 = lane & 7;
  const int arow = w * 8 + l8;                    // staging row within 64-row chunk
  const int schunk = (lc ^ l8) * 8;               // pre-swizzled source chunk (elements)
  const int w8 = w * 8;

  const bf16* Ag = feats + (size_t)mt * 256 * K4;
  const bf16* Bg = WT + (size_t)nt * 128 * K4;

  f32x4 acc[4][4];
  const f32x4 zero = {0.f, 0.f, 0.f, 0.f};
  #pragma unroll
  for (int i = 0; i < 4; i++)
    #pragma unroll
    for (int j = 0; j < 4; j++) acc[i][j] = zero;

  // stage one tile's A-chunk c (0..3) / B-chunk c (0..1) at k-offset k0 into buffer base
  #define STAGE_A(base, c, k0) \
    gload16(Ag + (size_t)((c) * 64 + arow) * K4 + (k0) + schunk, (base) + ((c) * 64 + w8) * 128)
  #define STAGE_B(base, c, k0) \
    gload16(Bg + (size_t)((c) * 64 + arow) * K4 + (k0) + schunk, (base) + 32768 + ((c) * 64 + w8) * 128)

  // frag reads with inverse swizzle
  #define LDA(base, i, kk) \
    (*(const bf16x8*)((base) + (wm * 64 + (i) * 16 + ar) * 128 + (((kk) * 4 + cg) ^ a7) * 16))
  #define LDB(base, j, kk) \
    (*(const bf16x8*)((base) + 32768 + (wn * 64 + (j) * 16 + ar) * 128 + (((kk) * 4 + cg) ^ a7) * 16))

  // prologue: stage tiles 0 (buf0) and 1 (buf1)
  {
    char* b0 = smem;
    STAGE_A(b0, 0, 0); STAGE_A(b0, 1, 0); STAGE_A(b0, 2, 0); STAGE_A(b0, 3, 0);
    STAGE_B(b0, 0, 0); STAGE_B(b0, 1, 0);
    char* b1 = smem + 49152;
    STAGE_A(b1, 0, 64); STAGE_A(b1, 1, 64); STAGE_A(b1, 2, 64); STAGE_A(b1, 3, 64);
    STAGE_B(b1, 0, 64); STAGE_B(b1, 1, 64);
  }
  asm volatile("s_waitcnt vmcnt(6)" ::: "memory");  // tile 0 landed
  __builtin_amdgcn_s_barrier();

  int rd = 0, st = 2;
  for (int kt = 0; kt < 64; kt++) {
    char* bA = smem + rd * 49152;
    char* sA = smem + st * 49152;
    const int k2 = (kt + 2) * 64;
    const bool do_stage = (kt + 2) < 64;
    bf16x8 a0[4], b0[4], a1[4], b1[4];

    // issue all LDS reads for this tile (compiler interleaves with MFMA via lgkmcnt)
    #pragma unroll
    for (int i = 0; i < 4; i++) a0[i] = LDA(bA, i, 0);
    #pragma unroll
    for (int j = 0; j < 4; j++) b0[j] = LDB(bA, j, 0);
    #pragma unroll
    for (int i = 0; i < 4; i++) a1[i] = LDA(bA, i, 1);
    #pragma unroll
    for (int j = 0; j < 4; j++) b1[j] = LDB(bA, j, 1);
    // issue next+1 tile's staging loads (VMEM, overlap with everything)
    if (do_stage) {
      STAGE_A(sA, 0, k2); STAGE_A(sA, 1, k2); STAGE_A(sA, 2, k2); STAGE_A(sA, 3, k2);
      STAGE_B(sA, 0, k2); STAGE_B(sA, 1, k2);
    }

    __builtin_amdgcn_s_setprio(1);
    #pragma unroll
    for (int i = 0; i < 4; i++)
      #pragma unroll
      for (int j = 0; j < 4; j++)
        acc[i][j] = __builtin_amdgcn_mfma_f32_16x16x32_bf16(a0[i], b0[j], acc[i][j], 0, 0, 0);
    #pragma unroll
    for (int i = 0; i < 4; i++)
      #pragma unroll
      for (int j = 0; j < 4; j++)
        acc[i][j] = __builtin_amdgcn_mfma_f32_16x16x32_bf16(a1[i], b1[j], acc[i][j], 0, 0, 0);
    __builtin_amdgcn_s_setprio(0);

    // one counted wait + one barrier per K-tile: tile kt+1's stages (issued at kt-1)
    // retired per-wave, published across waves by the barrier.
    if (do_stage) asm volatile("s_waitcnt vmcnt(6)" ::: "memory");
    else          asm volatile("s_waitcnt vmcnt(0)" ::: "memory");
    __builtin_amdgcn_s_barrier();

    rd = (rd == 2) ? 0 : rd + 1;
    st = (st == 2) ? 0 : st + 1;
  }
  #undef STAGE_A
  #undef STAGE_B
  #undef LDA
  #undef LDB

  // keep the K-loop's counted vmcnt semantics sealed: no VMEM op may be scheduled
  // above this point (e.g. the bqv load below) or vmcnt(6) would miscount.
  __builtin_amdgcn_sched_barrier(0);

  // epilogue: LDS repack -> coalesced float4 stores (4 passes of 64 rows)
  float* tile = (float*)smem;  // [64][132] = 33792 B
  const int cc = (t & 31) * 4;
  const float4 bq = *reinterpret_cast<const float4*>(bqv + nt * 128 + cc);
  __syncthreads();
  #pragma unroll
  for (int p = 0; p < 4; p++) {
    if (wm == p) {
      #pragma unroll
      for (int i = 0; i < 4; i++)
        #pragma unroll
        for (int j = 0; j < 4; j++)
          #pragma unroll
          for (int r = 0; r < 4; r++) {
            const int ml = i * 16 + (lane >> 4) * 4 + r;          // 0..63
            const int nl = wn * 64 + j * 16 + (lane & 15);
            tile[ml * 132 + nl] = acc[i][j][r];
          }
    }
    __syncthreads();
    #pragma unroll
    for (int itx = 0; itx < 4; itx++) {
      const int rr = itx * 16 + (t >> 5);                          // 0..63
      const f32x4 v = *reinterpret_cast<const f32x4*>(&tile[rr * 132 + cc]);
      float4 o;
      o.x = v[0] + bq.x; o.y = v[1] + bq.y; o.z = v[2] + bq.z; o.w = v[3] + bq.w;
      *reinterpret_cast<float4*>(out + (size_t)(mt * 256 + p * 64 + rr) * DD + nt * 128 + cc) = o;
    }
    __syncthreads();
  }
}

extern "C" void kernel_launch(void* const* d_in, const int* in_sizes, int n_in,
                              void* d_out, int out_size, void* d_ws, size_t ws_size,
                              hipStream_t stream) {
  const float* hc = (const float*)d_in[0];    // (16,512,1024)
  const float* hq = (const float*)d_in[1];    // (16,128,1024)
  const float* wsim = (const float*)d_in[2];  // (3072,)
  const float* bsim = (const float*)d_in[3];  // (1,)
  const float* Wqv = (const float*)d_in[4];   // (4096,1024)
  const float* bqv = (const float*)d_in[5];   // (1024,)
  float* out = (float*)d_out;                 // (16,512,1024)

  char* ws = (char*)d_ws;
  bf16* feats = (bf16*)(ws + OFF_FEATS);
  bf16* hqw3 = (bf16*)(ws + OFF_HQW3);
  bf16* hqT = (bf16*)(ws + OFF_HQT);
  bf16* WT = (bf16*)(ws + OFF_WT);
  bf16* Abf = (bf16*)(ws + OFF_ABF);
  float* s1 = (float*)(ws + OFF_S1);
  float* s2 = (float*)(ws + OFF_S2);
  float* mrow = (float*)(ws + OFF_MROW);
  float* hcbar = (float*)(ws + OFF_HCBAR);

  k_prep<<<MALL + BB * LD, 256, 0, stream>>>(hc, hq, wsim, feats, hqw3, s1, s2);
  // hq (16 x [128 x 1024]) -> hqT (16 x [1024 x 128])
  k_transpose<<<dim3(DD / 64, LD / 64, BB), 256, 0, stream>>>(hq, hqT, LD, DD,
                                                              (long)LD * DD, (long)DD * LD);
  // W_qv (4096 x 1024) -> WT (1024 x 4096)
  k_transpose<<<dim3(DD / 64, K4 / 64, 1), 256, 0, stream>>>(Wqv, WT, K4, DD, 0, 0);
  k_sim<<<dim3(BB, LE / 128), 256, 0, stream>>>(feats, hqw3, s1, s2, bsim, Abf, mrow);
  k_batt<<<dim3(BB, DD / 256), 256, 0, stream>>>(mrow, hc, hcbar);
  k_hqhat<<<dim3(BB, LE / 128, DD / 128), 256, 0, stream>>>(Abf, hqT, hc, hcbar, feats);
  k_final2<<<dim3(MALL / 256, DD / 128), 512, 0, stream>>>(feats, WT, bqv, out);
}